// Round 15
// baseline (1496.244 us; speedup 1.0000x reference)
//
#include <hip/hip_runtime.h>
#include <math.h>

// Problem dims
constexpr int S_   = 70;
constexpr int B_   = 16;
constexpr int SB_  = 1120;     // S*B
constexpr int NT_  = 32000;    // NTOKEN
constexpr int W1S_ = 32001;    // odeW1 row stride (NTOKEN+1)
constexpr int AST  = 424;      // ode kernel LDS A stride (ushorts)
constexpr int NO_  = 802;      // odeT N (800 + dvec + bvec columns)
constexpr int NOS  = 816;      // odeT partials row stride

typedef __attribute__((ext_vector_type(8))) short bf16x8;
typedef __attribute__((ext_vector_type(4))) float f32x4;

__device__ __forceinline__ float sigm(float x){ return 1.f/(1.f+__expf(-x)); }
__device__ __forceinline__ float softplusf(float x){ return x > 15.f ? x : log1pf(__expf(x)); }

__device__ __forceinline__ unsigned short f2bf(float f){
    union{float f; unsigned u;} c; c.f = f;
    unsigned u = c.u;
    unsigned r = (u + 0x7fffu + ((u >> 16) & 1u)) >> 16;
    return (unsigned short)r;
}
__device__ __forceinline__ float bfu(unsigned short us){
    union{unsigned u; float f;} c; c.u = ((unsigned)us) << 16; return c.f;
}

// ---------------------------------------------------------------------------
// All six LSTM weight conversions in one launch: fp32 [R][K] -> bf16 [R][Kp]
__global__ __launch_bounds__(256) void cvt_pack_all_k(
    const float* __restrict__ s0, unsigned short* __restrict__ d0,
    const float* __restrict__ s1, unsigned short* __restrict__ d1,
    const float* __restrict__ s2, unsigned short* __restrict__ d2,
    const float* __restrict__ s3, unsigned short* __restrict__ d3,
    const float* __restrict__ s4, unsigned short* __restrict__ d4,
    const float* __restrict__ s5, unsigned short* __restrict__ d5)
{
    int seg = blockIdx.y;
    const float* src; unsigned short* dst; int R, K, Kp;
    switch(seg){
      case 0: src=s0; dst=d0; R=4600; K=400;  Kp=416;  break;
      case 1: src=s1; dst=d1; R=4600; K=1150; Kp=1152; break;
      case 2: src=s2; dst=d2; R=4600; K=1150; Kp=1152; break;
      case 3: src=s3; dst=d3; R=4600; K=1150; Kp=1152; break;
      case 4: src=s4; dst=d4; R=1600; K=1150; Kp=1152; break;
      default:src=s5; dst=d5; R=1600; K=400;  Kp=416;  break;
    }
    long long idx = (long long)blockIdx.x*256 + threadIdx.x;
    long long tot = (long long)R*Kp;
    if (idx >= tot) return;
    int r = (int)(idx / Kp), kk = (int)(idx - (long long)r*Kp);
    float v = (kk < K) ? src[(size_t)r*K + kk] : 0.f;
    dst[idx] = f2bf(v);
}

// Fused: Bbf[32000][800] row-major AND BbfT[802][32000] transposed, single read.
// Rows 800/801 of BbfT = bf16(decb), bf16(odeb2) (for dvec/bvec via the GEMM).
__global__ __launch_bounds__(256) void cvt_catB2_k(const float* __restrict__ decW,
                                                   const float* __restrict__ odeW2,
                                                   const float* __restrict__ decb,
                                                   const float* __restrict__ b2v,
                                                   unsigned short* __restrict__ Bbf,
                                                   unsigned short* __restrict__ BbfT)
{
    __shared__ unsigned short tile[32][72];
    int v0 = blockIdx.x*64, n0 = blockIdx.y*32;
    int tx = threadIdx.x & 31;
    int vy = threadIdx.x >> 5;
    #pragma unroll
    for (int i = 0; i < 8; ++i){
        int v = v0 + i*8 + vy;
        int n = n0 + tx;
        float val;
        if      (n < 400) val = decW[(size_t)v*400 + n];
        else if (n < 800) val = odeW2[(size_t)v*400 + (n-400)];
        else if (n == 800) val = decb[v];
        else if (n == 801) val = b2v[v];
        else               val = 0.f;
        unsigned short us = f2bf(val);
        tile[tx][v - v0] = us;
        if (n < 800) Bbf[(size_t)v*800 + n] = us;
    }
    __syncthreads();
    int vx = threadIdx.x & 63;
    int ny = threadIdx.x >> 6;
    #pragma unroll
    for (int i = 0; i < 8; ++i){
        int n = n0 + i*4 + ny;
        if (n < NO_) BbfT[(size_t)n*NT_ + v0 + vx] = tile[n - n0][vx];
    }
}

// Wxbf[400][32000] = bf16(odeW1[:,1:])
__global__ __launch_bounds__(256) void cvt_wx_k(const float* __restrict__ odeW1,
                                                unsigned short* __restrict__ Wxbf)
{
    long long idx = (long long)blockIdx.x*256 + threadIdx.x;
    if (idx >= (long long)400*NT_) return;
    int m = (int)(idx / NT_), v = (int)(idx - (long long)m*NT_);
    Wxbf[idx] = f2bf(odeW1[(size_t)m*W1S_ + 1 + v]);
}

// ---------------------------------------------------------------------------
// Fused setup: embedding gather + h0 bf16 conversions + c0 transposes.
__global__ __launch_bounds__(256) void setup_all_k(
    const int* __restrict__ tok, const float* __restrict__ emb,
    unsigned short* __restrict__ x0A,
    const float* __restrict__ h00, unsigned short* __restrict__ h0b,
    const float* __restrict__ h01, unsigned short* __restrict__ h1b,
    const float* __restrict__ h02, unsigned short* __restrict__ h2b,
    const float* __restrict__ c00, float* __restrict__ c0b,
    const float* __restrict__ c01, float* __restrict__ c1b,
    const float* __restrict__ c02, float* __restrict__ c2b)
{
    int blk = blockIdx.x;
    if (blk < 70){
        int t = blk;
        __shared__ int tk[16];
        if (threadIdx.x < 16) tk[threadIdx.x] = tok[t*16 + threadIdx.x];
        __syncthreads();
        for (int idx = threadIdx.x; idx < 16*416; idx += 256){
            int b = idx / 416, k = idx - b*416;
            float v = (k < 400) ? emb[(size_t)tk[b]*400 + k] : 0.f;
            x0A[(size_t)t*16*416 + idx] = f2bf(v);
        }
        return;
    }
    blk -= 70;
    const float* hs = nullptr; unsigned short* hd = nullptr; int Dh, SA;
    if      (blk < 72) { hs = h00; hd = h0b; Dh = 1150; SA = 1152; }
    else if (blk < 144){ hs = h01; hd = h1b; Dh = 1150; SA = 1152; blk -= 72; }
    else if (blk < 169){ hs = h02; hd = h2b; Dh = 400;  SA = 416;  blk -= 144; }
    if (hs){
        int idx = blk*256 + threadIdx.x;
        if (idx < 16*Dh){
            int b = idx / Dh, j = idx - b*Dh;
            hd[(size_t)b*SA + j] = f2bf(hs[idx]);
        }
        return;
    }
    blk -= 169;
    const float* cs; float* cd; int Dc;
    if      (blk < 72) { cs = c00; cd = c0b; Dc = 1150; }
    else if (blk < 144){ cs = c01; cd = c1b; Dc = 1150; blk -= 72; }
    else               { cs = c02; cd = c2b; Dc = 400;  blk -= 144; }
    int idx = blk*256 + threadIdx.x;
    if (idx < Dc*16){
        int j = idx >> 4, b = idx & 15;
        cd[idx] = cs[b*Dc + j];
    }
}

// ---------------------------------------------------------------------------
// K-segment dot with 4 accumulator chains.
__device__ __forceinline__ void dotseg(const unsigned short* __restrict__ a,
                                       const unsigned short* __restrict__ b,
                                       int s, int e, int kq,
                                       f32x4& c0, f32x4& c1, f32x4& c2, f32x4& c3)
{
    int k0 = s;
    for (; k0 + 128 <= e; k0 += 128){
        bf16x8 a0 = *(const bf16x8*)(a + k0 + kq);
        bf16x8 b0 = *(const bf16x8*)(b + k0 + kq);
        bf16x8 a1 = *(const bf16x8*)(a + k0 + 32 + kq);
        bf16x8 b1 = *(const bf16x8*)(b + k0 + 32 + kq);
        bf16x8 a2 = *(const bf16x8*)(a + k0 + 64 + kq);
        bf16x8 b2 = *(const bf16x8*)(b + k0 + 64 + kq);
        bf16x8 a3 = *(const bf16x8*)(a + k0 + 96 + kq);
        bf16x8 b3 = *(const bf16x8*)(b + k0 + 96 + kq);
        c0 = __builtin_amdgcn_mfma_f32_16x16x32_bf16(a0, b0, c0, 0,0,0);
        c1 = __builtin_amdgcn_mfma_f32_16x16x32_bf16(a1, b1, c1, 0,0,0);
        c2 = __builtin_amdgcn_mfma_f32_16x16x32_bf16(a2, b2, c2, 0,0,0);
        c3 = __builtin_amdgcn_mfma_f32_16x16x32_bf16(a3, b3, c3, 0,0,0);
    }
    int rem = e - k0;
    if (rem >= 32){
        bf16x8 a0 = *(const bf16x8*)(a + k0 + kq);
        bf16x8 b0 = *(const bf16x8*)(b + k0 + kq);
        c0 = __builtin_amdgcn_mfma_f32_16x16x32_bf16(a0, b0, c0, 0,0,0);
    }
    if (rem >= 64){
        bf16x8 a1 = *(const bf16x8*)(a + k0 + 32 + kq);
        bf16x8 b1 = *(const bf16x8*)(b + k0 + 32 + kq);
        c1 = __builtin_amdgcn_mfma_f32_16x16x32_bf16(a1, b1, c1, 0,0,0);
    }
    if (rem >= 96){
        bf16x8 a2 = *(const bf16x8*)(a + k0 + 64 + kq);
        bf16x8 b2 = *(const bf16x8*)(b + k0 + 64 + kq);
        c2 = __builtin_amdgcn_mfma_f32_16x16x32_bf16(a2, b2, c2, 0,0,0);
    }
}

// ---------------------------------------------------------------------------
// Upfront layer-0 x-projection: xp0[t][g*1150+j][b] = x0[t,b,:]·Wih0[g*1150+j,:]
__global__ __launch_bounds__(1024) void xproj0_k(const unsigned short* __restrict__ x0A,
                                                 const unsigned short* __restrict__ Wih0p,
                                                 unsigned short* __restrict__ xp0)
{
    int jt = blockIdx.x, t = blockIdx.y;
    int j0 = jt*16;
    int lane = threadIdx.x & 63, w = threadIdx.x >> 6;
    int gate = w & 3, seg = w >> 2;
    int am = lane & 15, kq = (lane >> 4)*8, jn = lane & 15;
    int jrow = j0 + jn; if (jrow > 1149) jrow = 1149;

    const unsigned short* ax = x0A + (size_t)t*16*416 + (size_t)am*416;
    const unsigned short* wx = Wih0p + (size_t)(gate*1150 + jrow)*416;
    int nk = 416 >> 5;
    int q0 = ((nk*seg) >> 2) << 5, q1 = ((nk*(seg+1)) >> 2) << 5;
    f32x4 c0v={0.f,0.f,0.f,0.f},c1v={0.f,0.f,0.f,0.f},c2v={0.f,0.f,0.f,0.f},c3v={0.f,0.f,0.f,0.f};
    dotseg(ax, wx, q0, q1, kq, c0v, c1v, c2v, c3v);
    f32x4 acc = (c0v + c1v) + (c2v + c3v);

    __shared__ float g16[16][16][17];
    int bm = (lane >> 4)*4;
    #pragma unroll
    for (int r = 0; r < 4; ++r) g16[w][bm + r][jn] = acc[r];
    __syncthreads();
    if (threadIdx.x < 256){
        int jl = threadIdx.x >> 4, b = threadIdx.x & 15;
        int j = j0 + jl;
        if (j < 1150){
            unsigned short* xp = xp0 + (size_t)t*4600*16;
            #pragma unroll
            for (int g = 0; g < 4; ++g){
                float s = g16[g][b][jl] + g16[g+4][b][jl] + g16[g+8][b][jl] + g16[g+12][b][jl];
                xp[((size_t)(g*1150 + j))*16 + b] = f2bf(s);
            }
        }
    }
}

// ---------------------------------------------------------------------------
// Deep-pipelined LSTM wavefront step. 266 blocks, all block-local.
__global__ __launch_bounds__(1024) void lstm_step2_k(int u,
    unsigned short* __restrict__ ys0A, unsigned short* __restrict__ ys1A,
    float* __restrict__ x3,
    unsigned short* __restrict__ h0b, float* __restrict__ c0,
    unsigned short* __restrict__ h1b, float* __restrict__ c1,
    unsigned short* __restrict__ h2b, float* __restrict__ c2,
    const unsigned short* __restrict__ Whh0p, const float* __restrict__ bih0, const float* __restrict__ bhh0,
    const unsigned short* __restrict__ Wih1p, const unsigned short* __restrict__ Whh1p,
    const float* __restrict__ bih1, const float* __restrict__ bhh1,
    const unsigned short* __restrict__ Wih2p, const unsigned short* __restrict__ Whh2p,
    const float* __restrict__ bih2, const float* __restrict__ bhh2,
    const unsigned short* __restrict__ xp0,
    unsigned short* __restrict__ xp1, unsigned short* __restrict__ xp2)
{
    int blk = blockIdx.x;
    int role, jt;
    if      (blk < 72) { role = 0; jt = blk; }
    else if (blk < 144){ role = 1; jt = blk - 72; }
    else if (blk < 216){ role = 2; jt = blk - 144; }
    else if (blk < 241){ role = 3; jt = blk - 216; }
    else               { role = 4; jt = blk - 241; }
    int t = u - role;
    if (t < 0 || t >= S_) return;
    int j0 = jt*16;

    int lane = threadIdx.x & 63, w = threadIdx.x >> 6;
    int gate = w & 3, seg = w >> 2;
    int am = lane & 15, kq = (lane >> 4)*8, jn = lane & 15;

    __shared__ float g16[16][16][17];

    if (role == 1 || role == 3){
        const unsigned short *A, *Wi; int Dh; unsigned short* xp;
        if (role == 1){ A = ys0A + (size_t)t*16*1152; Wi = Wih1p; Dh = 1150; xp = xp1 + (size_t)t*4600*16; }
        else          { A = ys1A + (size_t)t*16*1152; Wi = Wih2p; Dh = 400;  xp = xp2 + (size_t)t*1600*16; }
        int jrow = j0 + jn; if (jrow > Dh-1) jrow = Dh-1;
        const unsigned short* ax = A + (size_t)am*1152;
        const unsigned short* wx = Wi + (size_t)(gate*Dh + jrow)*1152;
        int nk = 1152 >> 5;
        int q0 = ((nk*seg) >> 2) << 5, q1 = ((nk*(seg+1)) >> 2) << 5;
        f32x4 c0v={0.f,0.f,0.f,0.f},c1v={0.f,0.f,0.f,0.f},c2v={0.f,0.f,0.f,0.f},c3v={0.f,0.f,0.f,0.f};
        dotseg(ax, wx, q0, q1, kq, c0v, c1v, c2v, c3v);
        f32x4 acc = (c0v + c1v) + (c2v + c3v);
        int bm = (lane >> 4)*4;
        #pragma unroll
        for (int r = 0; r < 4; ++r) g16[w][bm + r][jn] = acc[r];
        __syncthreads();
        if (threadIdx.x < 256){
            int jl = threadIdx.x >> 4, b = threadIdx.x & 15;
            int j = j0 + jl;
            if (j < Dh){
                #pragma unroll
                for (int g = 0; g < 4; ++g){
                    float s = g16[g][b][jl] + g16[g+4][b][jl] + g16[g+8][b][jl] + g16[g+12][b][jl];
                    xp[((size_t)(g*Dh + j))*16 + b] = f2bf(s);
                }
            }
        }
    } else {
        const unsigned short *Ah, *Wh, *xp;
        const float *bih, *bhh;
        float *cst, *x3o = nullptr;
        unsigned short *yo = nullptr, *hrec;
        int Dh, SAh, Kh;
        if (role == 0){
            Ah = h0b + (size_t)(t&1)*16*1152; SAh = 1152; Kh = 1152;
            Wh = Whh0p; bih = bih0; bhh = bhh0; Dh = 1150;
            cst = c0; hrec = h0b + (size_t)((t+1)&1)*16*1152;
            yo = ys0A + (size_t)t*16*1152;
            xp = xp0 + (size_t)t*4600*16;
        } else if (role == 2){
            Ah = h1b + (size_t)(t&1)*16*1152; SAh = 1152; Kh = 1152;
            Wh = Whh1p; bih = bih1; bhh = bhh1; Dh = 1150;
            cst = c1; hrec = h1b + (size_t)((t+1)&1)*16*1152;
            yo = ys1A + (size_t)t*16*1152;
            xp = xp1 + (size_t)t*4600*16;
        } else {
            Ah = h2b + (size_t)(t&1)*16*416; SAh = 416; Kh = 416;
            Wh = Whh2p; bih = bih2; bhh = bhh2; Dh = 400;
            cst = c2; hrec = h2b + (size_t)((t+1)&1)*16*416;
            x3o = x3 + (size_t)t*16*400;
            xp = xp2 + (size_t)t*1600*16;
        }
        int jrow = j0 + jn; if (jrow > Dh-1) jrow = Dh-1;
        const unsigned short* ah = Ah + (size_t)am*SAh;
        const unsigned short* wh = Wh + (size_t)(gate*Dh + jrow)*SAh;
        int nk = Kh >> 5;
        int q0 = ((nk*seg) >> 2) << 5, q1 = ((nk*(seg+1)) >> 2) << 5;
        f32x4 c0v={0.f,0.f,0.f,0.f},c1v={0.f,0.f,0.f,0.f},c2v={0.f,0.f,0.f,0.f},c3v={0.f,0.f,0.f,0.f};
        dotseg(ah, wh, q0, q1, kq, c0v, c1v, c2v, c3v);
        f32x4 acc = (c0v + c1v) + (c2v + c3v);
        int bm = (lane >> 4)*4;
        #pragma unroll
        for (int r = 0; r < 4; ++r) g16[w][bm + r][jn] = acc[r];
        __syncthreads();
        if (threadIdx.x < 256){
            int jl = threadIdx.x >> 4, b = threadIdx.x & 15;
            int j = j0 + jl;
            if (j < Dh){
                float pi = g16[0][b][jl] + g16[4][b][jl] + g16[8][b][jl]  + g16[12][b][jl]
                         + bfu(xp[((size_t)(0*Dh + j))*16 + b]) + bih[j]      + bhh[j];
                float pf = g16[1][b][jl] + g16[5][b][jl] + g16[9][b][jl]  + g16[13][b][jl]
                         + bfu(xp[((size_t)(1*Dh + j))*16 + b]) + bih[Dh+j]   + bhh[Dh+j];
                float pg = g16[2][b][jl] + g16[6][b][jl] + g16[10][b][jl] + g16[14][b][jl]
                         + bfu(xp[((size_t)(2*Dh + j))*16 + b]) + bih[2*Dh+j] + bhh[2*Dh+j];
                float po = g16[3][b][jl] + g16[7][b][jl] + g16[11][b][jl] + g16[15][b][jl]
                         + bfu(xp[((size_t)(3*Dh + j))*16 + b]) + bih[3*Dh+j] + bhh[3*Dh+j];
                float cold = cst[j*16 + b];
                float cnew = sigm(pf)*cold + sigm(pi)*tanhf(pg);
                float h    = sigm(po)*tanhf(cnew);
                cst[j*16 + b] = cnew;
                unsigned short hb16 = f2bf(h);
                hrec[(size_t)b*SAh + j] = hb16;
                if (yo)  yo[(size_t)b*1152 + j] = hb16;
                if (x3o) x3o[(size_t)b*400 + j] = h;
            }
        }
    }
}

// ---------------------------------------------------------------------------
// MFMA ODE precompute, LDS stride 44, 16 K-slabs, N=802 (incl dvec/bvec cols),
// XCD-chunked block swizzle (448 blocks, 448%8==0).
__global__ __launch_bounds__(256) void gemm_odeT_k(
    const unsigned short* __restrict__ Wxbf,
    const unsigned short* __restrict__ BbfT,
    float* __restrict__ partials)
{
    __shared__ unsigned short As[128*44];
    __shared__ unsigned short Bs[128*44];
    int lin = blockIdx.x + 7*(blockIdx.y + 4*blockIdx.z);   // [0,448)
    int swz = (lin & 7)*56 + (lin >> 3);
    int xt = swz % 7, rem = swz / 7;
    int yt = rem & 3, zt = rem >> 2;
    int n0 = xt*128, m0 = yt*128, v0 = zt*2000;
    int tid = threadIdx.x;
    int lane = tid & 63, wid = tid >> 6;
    int wr = wid >> 1, wc = wid & 1;
    f32x4 acc[4][4] = {};

    int srow = tid >> 1;
    int sk   = (tid & 1) * 16;
    int mL = m0 + srow; if (mL > 399) mL = 399;
    int nL = n0 + srow; if (nL > NO_-1) nL = NO_-1;
    const unsigned short* ap = Wxbf + (size_t)mL*NT_ + v0 + sk;
    const unsigned short* bp = BbfT + (size_t)nL*NT_ + v0 + sk;

    for (int k0 = 0; k0 < 2000; k0 += 32){
        uint4 av0 = *(const uint4*)(ap + k0);
        uint4 av1 = *(const uint4*)(ap + k0 + 8);
        uint4 bv0 = *(const uint4*)(bp + k0);
        uint4 bv1 = *(const uint4*)(bp + k0 + 8);

        __syncthreads();
        *(uint4*)&As[srow*44 + sk]     = av0;
        *(uint4*)&As[srow*44 + sk + 8] = av1;
        *(uint4*)&Bs[srow*44 + sk]     = bv0;
        *(uint4*)&Bs[srow*44 + sk + 8] = bv1;
        __syncthreads();

        int kq = (lane >> 4) * 8;
        int rA = wr*64 + (lane & 15);
        int rB = wc*64 + (lane & 15);
        bf16x8 af[4], bfv[4];
        #pragma unroll
        for (int f = 0; f < 4; ++f){
            af[f]  = *(const bf16x8*)&As[(rA + f*16)*44 + kq];
            bfv[f] = *(const bf16x8*)&Bs[(rB + f*16)*44 + kq];
        }
        #pragma unroll
        for (int fm = 0; fm < 4; ++fm)
            #pragma unroll
            for (int fn = 0; fn < 4; ++fn)
                acc[fm][fn] = __builtin_amdgcn_mfma_f32_16x16x32_bf16(af[fm], bfv[fn], acc[fm][fn], 0, 0, 0);
    }

    float* op = partials + (size_t)zt*400*NOS;
    int cm = (lane >> 4) * 4;
    int cn = lane & 15;
    #pragma unroll
    for (int fm = 0; fm < 4; ++fm){
        int mrow0 = m0 + wr*64 + fm*16 + cm;
        #pragma unroll
        for (int fn = 0; fn < 4; ++fn){
            int n = n0 + wc*64 + fn*16 + cn;
            if (n >= NO_) continue;
            #pragma unroll
            for (int r = 0; r < 4; ++r){
                int mr = mrow0 + r;
                if (mr < 400) op[mr*NOS + n] = acc[fm][fn][r];
            }
        }
    }
}

// sum 16 slabs; scatter: n<400 -> Qbf, 400..799 -> Pbf, 800 -> dvec, 801 -> bvec.
__global__ __launch_bounds__(256) void reduce16v_k(const float* __restrict__ p,
                                                   const float* __restrict__ odeW1,
                                                   unsigned short* __restrict__ Qbf,
                                                   unsigned short* __restrict__ Pbf,
                                                   float* __restrict__ dvec,
                                                   float* __restrict__ bvec,
                                                   float* __restrict__ wtd)
{
    int i = blockIdx.x*256 + threadIdx.x;
    if (i < 400) wtd[i] = odeW1[(size_t)i*W1S_];
    if (i >= 400*NO_) return;
    int m = i / NO_, n = i - m*NO_;
    float s = 0.f;
    #pragma unroll
    for (int k = 0; k < 16; ++k) s += p[(size_t)k*400*NOS + m*NOS + n];
    if      (n < 400) Qbf[m*416 + n] = f2bf(s);
    else if (n < 800) Pbf[m*416 + (n-400)] = f2bf(s);
    else if (n == 800) dvec[m] = s;
    else               bvec[m] = s;
}

// ---------------------------------------------------------------------------
// FUSED ODE: G0 GEMM + 2 RK4 steps + Gy update + Abf output.
__global__ __launch_bounds__(512) void ode_rk4_k(
    const float* __restrict__ x3,
    const unsigned short* __restrict__ Qbf,
    const unsigned short* __restrict__ Pbf,
    const float* __restrict__ dvec, const float* __restrict__ bvec,
    const float* __restrict__ wtd, const float* __restrict__ b1,
    unsigned short* __restrict__ Abf)
{
    __shared__ unsigned short Al[16*AST];
    int m0 = blockIdx.x*16;
    int tid = threadIdx.x;
    int lane = tid & 63, ng = tid >> 6;
    int cm = (lane >> 4)*4;
    int cn = lane & 15;
    int kq = (lane >> 4)*8;

    #pragma unroll
    for (int i = 0; i < 13; ++i){
        int idx = i*512 + tid;
        if (idx < 6400){
            int m = idx / 400, k = idx - m*400;
            unsigned short us = f2bf(x3[(size_t)(m0+m)*400 + k]);
            Al[m*AST + k] = us;
            Abf[(size_t)(m0+m)*800 + k] = us;
        }
    }
    if (tid < 256){ Al[(tid>>4)*AST + 400 + (tid & 15)] = 0; }
    __syncthreads();

    float gy[4][4], hacc[4][4], comb[4][4];
    float vd[4], vb[4], vw[4], v1[4];
    #pragma unroll
    for (int i = 0; i < 4; ++i){
        int nt = ng + 8*i;
        if (nt < 25){
            int n = nt*16 + cn;
            vd[i] = dvec[n]; vb[i] = bvec[n]; vw[i] = wtd[n]; v1[i] = b1[n];
        } else { vd[i]=0.f; vb[i]=0.f; vw[i]=0.f; v1[i]=0.f; }
        #pragma unroll
        for (int r = 0; r < 4; ++r) hacc[i][r] = 0.f;
    }

    const unsigned short* arow = &Al[(size_t)cn*AST + kq];
    f32x4 t4[4];
    auto gemmB = [&](const unsigned short* Bb){
        #pragma unroll
        for (int i = 0; i < 4; ++i){
            f32x4 a = {0.f,0.f,0.f,0.f};
            int nt = ng + 8*i;
            if (nt < 25){
                const unsigned short* brow = Bb + (size_t)(nt*16 + cn)*416 + kq;
                #pragma unroll
                for (int k0 = 0; k0 < 416; k0 += 32){
                    bf16x8 av = *(const bf16x8*)(arow + k0);
                    bf16x8 bv = *(const bf16x8*)(brow + k0);
                    a = __builtin_amdgcn_mfma_f32_16x16x32_bf16(av, bv, a, 0,0,0);
                }
            }
            t4[i] = a;
        }
    };
    auto writeA = [&](float vals[4][4]){
        __syncthreads();
        #pragma unroll
        for (int i = 0; i < 4; ++i){
            int nt = ng + 8*i;
            if (nt < 25){
                int n = nt*16 + cn;
                #pragma unroll
                for (int r = 0; r < 4; ++r)
                    Al[(cm + r)*AST + n] = f2bf(vals[i][r]);
            }
        }
        __syncthreads();
    };

    gemmB(Qbf);
    #pragma unroll
    for (int i = 0; i < 4; ++i)
        #pragma unroll
        for (int r = 0; r < 4; ++r) gy[i][r] = t4[i][r] + vd[i];

    const float dt = 0.5f;
    for (int st = 0; st < 2; ++st){
        float t0 = st * dt;
        float hs[4][4];
        #pragma unroll
        for (int i = 0; i < 4; ++i)
            #pragma unroll
            for (int r = 0; r < 4; ++r){
                float v = softplusf(gy[i][r] + t0*vw[i] + v1[i]);
                hs[i][r] = v; comb[i][r] = v;
            }
        writeA(hs);
        gemmB(Pbf);
        #pragma unroll
        for (int i = 0; i < 4; ++i)
            #pragma unroll
            for (int r = 0; r < 4; ++r){
                float v = softplusf(0.25f*t4[i][r] + gy[i][r] + 0.25f*vb[i] + (t0+0.25f)*vw[i] + v1[i]);
                hs[i][r] = v; comb[i][r] += 2.f*v;
            }
        writeA(hs);
        gemmB(Pbf);
        #pragma unroll
        for (int i = 0; i < 4; ++i)
            #pragma unroll
            for (int r = 0; r < 4; ++r){
                float v = softplusf(0.25f*t4[i][r] + gy[i][r] + 0.25f*vb[i] + (t0+0.25f)*vw[i] + v1[i]);
                hs[i][r] = v; comb[i][r] += 2.f*v;
            }
        writeA(hs);
        gemmB(Pbf);
        #pragma unroll
        for (int i = 0; i < 4; ++i)
            #pragma unroll
            for (int r = 0; r < 4; ++r){
                float v = softplusf(0.5f*t4[i][r] + gy[i][r] + 0.5f*vb[i] + (t0+0.5f)*vw[i] + v1[i]);
                comb[i][r] += v;
            }
        #pragma unroll
        for (int i = 0; i < 4; ++i)
            #pragma unroll
            for (int r = 0; r < 4; ++r){
                float v = comb[i][r] * (1.f/12.f);
                comb[i][r] = v;
                hacc[i][r] += v;
            }
        if (st == 0){
            writeA(comb);
            gemmB(Pbf);
            #pragma unroll
            for (int i = 0; i < 4; ++i)
                #pragma unroll
                for (int r = 0; r < 4; ++r) gy[i][r] += t4[i][r] + dt*vb[i];
        }
    }

    #pragma unroll
    for (int i = 0; i < 4; ++i){
        int nt = ng + 8*i;
        if (nt < 25){
            int n = nt*16 + cn;
            #pragma unroll
            for (int r = 0; r < 4; ++r){
                int m = m0 + cm + r;
                Abf[(size_t)m*800 + 400 + n] = f2bf(hacc[i][r]);
            }
        }
    }
}

// ---------------------------------------------------------------------------
// MFMA decode, 256x128 tiles, LDS stride 44, bf16 output zb.
// Grid = (5 m-tiles, 250 n-tiles): x-fastest dispatch runs the 5 m-tiles of
// one B n-panel back-to-back -> 0.2 MB panel stays L2-resident (5x reuse),
// cutting HBM FETCH from ~140 MB (B streamed 5x) to ~B-once + A-5x.
__global__ __launch_bounds__(512) void decode_mfma_k(
    const unsigned short* __restrict__ Abf,
    const unsigned short* __restrict__ Bbf,
    const float* __restrict__ decb, const float* __restrict__ b2v,
    unsigned short* __restrict__ zb)
{
    __shared__ unsigned short As[256*44];
    __shared__ unsigned short Bs[128*44];
    int n0 = blockIdx.y*128, m0 = blockIdx.x*256;
    int tid = threadIdx.x;
    int lane = tid & 63, wid = tid >> 6;
    int wr = wid >> 1, wc = wid & 1;
    f32x4 acc[4][4] = {};

    int srA = tid >> 1, skA = (tid & 1)*16;
    int srB = tid >> 2, skB = (tid & 3)*8;

    for (int k0 = 0; k0 < 800; k0 += 32){
        uint4 av0 = {0,0,0,0}, av1 = {0,0,0,0};
        int m = m0 + srA;
        if (m < SB_){
            const uint4* ap = (const uint4*)(Abf + (size_t)m*800 + k0 + skA);
            av0 = ap[0]; av1 = ap[1];
        }
        uint4 bv = *(const uint4*)(Bbf + (size_t)(n0 + srB)*800 + k0 + skB);

        __syncthreads();
        *(uint4*)&As[srA*44 + skA]     = av0;
        *(uint4*)&As[srA*44 + skA + 8] = av1;
        *(uint4*)&Bs[srB*44 + skB]     = bv;
        __syncthreads();

        int kq = (lane >> 4) * 8;
        int rA = wr*64 + (lane & 15);
        int rB = wc*64 + (lane & 15);
        bf16x8 af[4], bfv[4];
        #pragma unroll
        for (int f = 0; f < 4; ++f){
            af[f]  = *(const bf16x8*)&As[(rA + f*16)*44 + kq];
            bfv[f] = *(const bf16x8*)&Bs[(rB + f*16)*44 + kq];
        }
        #pragma unroll
        for (int fm = 0; fm < 4; ++fm)
            #pragma unroll
            for (int fn = 0; fn < 4; ++fn)
                acc[fm][fn] = __builtin_amdgcn_mfma_f32_16x16x32_bf16(af[fm], bfv[fn], acc[fm][fn], 0, 0, 0);
    }

    int cm = (lane >> 4) * 4;
    int cn = lane & 15;
    #pragma unroll
    for (int fm = 0; fm < 4; ++fm){
        int mrow0 = m0 + wr*64 + fm*16 + cm;
        #pragma unroll
        for (int fn = 0; fn < 4; ++fn){
            int n = n0 + wc*64 + fn*16 + cn;
            float db = decb[n] + b2v[n];
            #pragma unroll
            for (int r = 0; r < 4; ++r){
                int mr = mrow0 + r;
                if (mr < SB_) zb[(size_t)mr*NT_ + n] = f2bf(acc[fm][fn][r] + db);
            }
        }
    }
}

// ---------------------------------------------------------------------------
// Fused log-softmax: reads bf16 zb, row resident in registers, writes fp32 out.
__global__ __launch_bounds__(1024) void softmax_k(const unsigned short* __restrict__ zb,
                                                  float* __restrict__ zout)
{
    int r = blockIdx.x;
    const unsigned short* zr = zb + (size_t)r*NT_;
    float* zo = zout + (size_t)r*NT_;
    int tid = threadIdx.x;
    __shared__ float sm[1024];
    float4 v[8];
    float mx = -1e30f;
    #pragma unroll
    for (int i = 0; i < 8; ++i){
        int base = i*4096 + tid*4;
        if (base < NT_){
            ushort4 u = *(const ushort4*)(zr + base);
            v[i].x = bfu(u.x); v[i].y = bfu(u.y); v[i].z = bfu(u.z); v[i].w = bfu(u.w);
            mx = fmaxf(mx, fmaxf(fmaxf(v[i].x, v[i].y), fmaxf(v[i].z, v[i].w)));
        } else {
            v[i].x = v[i].y = v[i].z = v[i].w = 0.f;
        }
    }
    sm[tid] = mx; __syncthreads();
    for (int s = 512; s > 0; s >>= 1){
        if (tid < s) sm[tid] = fmaxf(sm[tid], sm[tid+s]);
        __syncthreads();
    }
    mx = sm[0]; __syncthreads();
    float sum = 0.f;
    #pragma unroll
    for (int i = 0; i < 8; ++i){
        int base = i*4096 + tid*4;
        if (base < NT_){
            sum += __expf(v[i].x - mx) + __expf(v[i].y - mx)
                 + __expf(v[i].z - mx) + __expf(v[i].w - mx);
        }
    }
    sm[tid] = sum; __syncthreads();
    for (int s = 512; s > 0; s >>= 1){
        if (tid < s) sm[tid] += sm[tid+s];
        __syncthreads();
    }
    float sinv = 1.f / sm[0];
    #pragma unroll
    for (int i = 0; i < 8; ++i){
        int base = i*4096 + tid*4;
        if (base < NT_){
            float4 o;
            o.x = logf(__expf(v[i].x - mx)*sinv + 1e-8f);
            o.y = logf(__expf(v[i].y - mx)*sinv + 1e-8f);
            o.z = logf(__expf(v[i].z - mx)*sinv + 1e-8f);
            o.w = logf(__expf(v[i].w - mx)*sinv + 1e-8f);
            *(float4*)(zo + base) = o;
        }
    }
}

// ---------------------------------------------------------------------------
extern "C" void kernel_launch(void* const* d_in, const int* in_sizes, int n_in,
                              void* d_out, int out_size, void* d_ws, size_t ws_size,
                              hipStream_t stream)
{
    const int*   tokens = (const int*)  d_in[0];
    const float* h0_0 = (const float*)d_in[1];
    const float* c0_0 = (const float*)d_in[2];
    const float* Wih0 = (const float*)d_in[3];
    const float* Whh0 = (const float*)d_in[4];
    const float* bih0 = (const float*)d_in[5];
    const float* bhh0 = (const float*)d_in[6];
    const float* h0_1 = (const float*)d_in[7];
    const float* c0_1 = (const float*)d_in[8];
    const float* Wih1 = (const float*)d_in[9];
    const float* Whh1 = (const float*)d_in[10];
    const float* bih1 = (const float*)d_in[11];
    const float* bhh1 = (const float*)d_in[12];
    const float* h0_2 = (const float*)d_in[13];
    const float* c0_2 = (const float*)d_in[14];
    const float* Wih2 = (const float*)d_in[15];
    const float* Whh2 = (const float*)d_in[16];
    const float* bih2 = (const float*)d_in[17];
    const float* bhh2 = (const float*)d_in[18];
    const float* emb  = (const float*)d_in[19];
    const float* decW = (const float*)d_in[20];
    const float* decb = (const float*)d_in[21];
    const float* odeW1= (const float*)d_in[22];
    const float* odeb1= (const float*)d_in[23];
    const float* odeW2= (const float*)d_in[24];
    const float* odeb2= (const float*)d_in[25];

    // workspace carve-up, all chunks 16B-aligned (~226 MB)
    float* w = (float*)d_ws;
    size_t off = 0;
    auto alloc = [&](size_t n){ float* p = w + off; off += n; return p; };
    auto allocU = [&](size_t nUsh){ return (unsigned short*)alloc(nUsh/2); };
    unsigned short* x0A  = allocU((size_t)S_*16*416);
    unsigned short* ys0A = allocU((size_t)S_*16*1152);
    unsigned short* ys1A = allocU((size_t)S_*16*1152);
    float* x3   = alloc((size_t)SB_*400);
    unsigned short* h0b = allocU((size_t)2*16*1152); float* c0b = alloc(1152*16);
    unsigned short* h1b = allocU((size_t)2*16*1152); float* c1b = alloc(1152*16);
    unsigned short* h2b = allocU((size_t)2*16*416);  float* c2b = alloc(416*16);
    unsigned short* Qbf = allocU((size_t)416*416);
    unsigned short* Pbf = allocU((size_t)416*416);
    float* dvec = alloc(512);
    float* bvec = alloc(512);
    float* wtd  = alloc(512);
    unsigned short* xp0 = allocU((size_t)S_*4600*16);
    unsigned short* xp1 = allocU((size_t)S_*4600*16);
    unsigned short* xp2 = allocU((size_t)S_*1600*16);
    float* partials = alloc((size_t)16*400*NOS);
    unsigned short* Wih0p = allocU((size_t)4600*416);
    unsigned short* Whh0p = allocU((size_t)4600*1152);
    unsigned short* Wih1p = allocU((size_t)4600*1152);
    unsigned short* Whh1p = allocU((size_t)4600*1152);
    unsigned short* Wih2p = allocU((size_t)1600*1152);
    unsigned short* Whh2p = allocU((size_t)1600*416);
    unsigned short* Abf   = allocU((size_t)SB_*800);
    unsigned short* Bbf   = allocU((size_t)NT_*800);
    unsigned short* BbfT  = allocU((size_t)808*NT_);   // 802 rows used (+pad)
    unsigned short* Wxbf  = allocU((size_t)400*NT_);
    (void)ws_size; (void)in_sizes; (void)n_in; (void)out_size;

    // bf16 logits buffer aliases BbfT+Wxbf (dead after reduce16v): 71.7 MB < 77.4 MB
    unsigned short* zb = BbfT;

    float* zout = (float*)d_out;

    // zero pad-sensitive buffers (MFMA reads pads; must not be NaN)
    hipMemsetAsync(ys0A, 0, (size_t)S_*16*1152*2, stream);
    hipMemsetAsync(ys1A, 0, (size_t)S_*16*1152*2, stream);
    hipMemsetAsync(h0b,  0, (size_t)2*16*1152*2, stream);
    hipMemsetAsync(h1b,  0, (size_t)2*16*1152*2, stream);
    hipMemsetAsync(h2b,  0, (size_t)2*16*416*2, stream);
    hipMemsetAsync(Qbf,  0, (size_t)416*416*2, stream);
    hipMemsetAsync(Pbf,  0, (size_t)416*416*2, stream);

    // weight conversions (bf16, K zero-padded): all six in one launch
    auto cvtgrid = [](long long n){ return (unsigned)((n + 255) / 256); };
    cvt_pack_all_k<<<dim3(cvtgrid((long long)4600*1152), 6), 256, 0, stream>>>(
        Wih0, Wih0p, Whh0, Whh0p, Wih1, Wih1p, Whh1, Whh1p, Wih2, Wih2p, Whh2, Whh2p);
    cvt_catB2_k<<<dim3(500, 26), 256, 0, stream>>>(decW, odeW2, decb, odeb2, Bbf, BbfT);
    cvt_wx_k<<<cvtgrid((long long)400*NT_), 256, 0, stream>>>(odeW1, Wxbf);

    // fused setup: embed + h0 bf16 + c0 transpose (one launch)
    setup_all_k<<<408, 256, 0, stream>>>(tokens, emb, x0A,
        h0_0, h0b, h0_1, h1b, h0_2, h2b, c0_0, c0b, c0_1, c1b, c0_2, c2b);

    // upfront layer-0 input projections (all t, fully parallel)
    xproj0_k<<<dim3(72, 70), 1024, 0, stream>>>(x0A, Wih0p, xp0);

    // deep-pipelined LSTM wavefront: 5 stages, 266 blocks, block-local only
    for (int u = 0; u < S_ + 4; ++u)
        lstm_step2_k<<<266, 1024, 0, stream>>>(u, ys0A, ys1A, x3,
            h0b, c0b, h1b, c1b, h2b, c2b,
            Whh0p, bih0, bhh0, Wih1p, Whh1p, bih1, bhh1, Wih2p, Whh2p, bih2, bhh2,
            xp0, xp1, xp2);

    // ODE precompute: [Q|P|dvec|bvec] = Wx @ BbfT^T via MFMA (N=802), 16 K-slabs
    gemm_odeT_k<<<dim3(7,4,16), 256, 0, stream>>>(Wxbf, BbfT, partials);
    reduce16v_k<<<(400*NO_+255)/256, 256, 0, stream>>>(partials, odeW1, Qbf, Pbf, dvec, bvec, wtd);

    // Fused ODE: G0 + RK4(2 steps) + Abf (both halves) in one kernel
    ode_rk4_k<<<70, 512, 0, stream>>>(x3, Qbf, Pbf, dvec, bvec, wtd, odeb1, Abf);

    // MFMA decode (256x128 tiles, bf16 out, n-panel-major grid) + log-softmax
    decode_mfma_k<<<dim3(5,250), 512, 0, stream>>>(Abf, Bbf, decb, odeb2, zb);
    softmax_k<<<SB_, 1024, 0, stream>>>(zb, zout);
}

// Round 16
// 1488.463 us; speedup vs baseline: 1.0052x; 1.0052x over previous
//
#include <hip/hip_runtime.h>
#include <math.h>

// Problem dims
constexpr int S_   = 70;
constexpr int B_   = 16;
constexpr int SB_  = 1120;     // S*B
constexpr int NT_  = 32000;    // NTOKEN
constexpr int W1S_ = 32001;    // odeW1 row stride (NTOKEN+1)
constexpr int AST  = 424;      // ode kernel LDS A stride (ushorts)
constexpr int NO_  = 802;      // odeT N (800 + dvec + bvec columns)
constexpr int NOS  = 816;      // odeT partials row stride

typedef __attribute__((ext_vector_type(8))) short bf16x8;
typedef __attribute__((ext_vector_type(4))) float f32x4;

__device__ __forceinline__ float sigm(float x){ return 1.f/(1.f+__expf(-x)); }
__device__ __forceinline__ float softplusf(float x){ return x > 15.f ? x : log1pf(__expf(x)); }

__device__ __forceinline__ unsigned short f2bf(float f){
    union{float f; unsigned u;} c; c.f = f;
    unsigned u = c.u;
    unsigned r = (u + 0x7fffu + ((u >> 16) & 1u)) >> 16;
    return (unsigned short)r;
}
__device__ __forceinline__ float bfu(unsigned short us){
    union{unsigned u; float f;} c; c.u = ((unsigned)us) << 16; return c.f;
}

// ---------------------------------------------------------------------------
// All six LSTM weight conversions in one launch: fp32 [R][K] -> bf16 [R][Kp]
__global__ __launch_bounds__(256) void cvt_pack_all_k(
    const float* __restrict__ s0, unsigned short* __restrict__ d0,
    const float* __restrict__ s1, unsigned short* __restrict__ d1,
    const float* __restrict__ s2, unsigned short* __restrict__ d2,
    const float* __restrict__ s3, unsigned short* __restrict__ d3,
    const float* __restrict__ s4, unsigned short* __restrict__ d4,
    const float* __restrict__ s5, unsigned short* __restrict__ d5)
{
    int seg = blockIdx.y;
    const float* src; unsigned short* dst; int R, K, Kp;
    switch(seg){
      case 0: src=s0; dst=d0; R=4600; K=400;  Kp=416;  break;
      case 1: src=s1; dst=d1; R=4600; K=1150; Kp=1152; break;
      case 2: src=s2; dst=d2; R=4600; K=1150; Kp=1152; break;
      case 3: src=s3; dst=d3; R=4600; K=1150; Kp=1152; break;
      case 4: src=s4; dst=d4; R=1600; K=1150; Kp=1152; break;
      default:src=s5; dst=d5; R=1600; K=400;  Kp=416;  break;
    }
    long long idx = (long long)blockIdx.x*256 + threadIdx.x;
    long long tot = (long long)R*Kp;
    if (idx >= tot) return;
    int r = (int)(idx / Kp), kk = (int)(idx - (long long)r*Kp);
    float v = (kk < K) ? src[(size_t)r*K + kk] : 0.f;
    dst[idx] = f2bf(v);
}

// Fused: Bbf[32000][800] row-major AND BbfT[802][32000] transposed, single read.
// Rows 800/801 of BbfT = bf16(decb), bf16(odeb2) (for dvec/bvec via the GEMM).
__global__ __launch_bounds__(256) void cvt_catB2_k(const float* __restrict__ decW,
                                                   const float* __restrict__ odeW2,
                                                   const float* __restrict__ decb,
                                                   const float* __restrict__ b2v,
                                                   unsigned short* __restrict__ Bbf,
                                                   unsigned short* __restrict__ BbfT)
{
    __shared__ unsigned short tile[32][72];
    int v0 = blockIdx.x*64, n0 = blockIdx.y*32;
    int tx = threadIdx.x & 31;
    int vy = threadIdx.x >> 5;
    #pragma unroll
    for (int i = 0; i < 8; ++i){
        int v = v0 + i*8 + vy;
        int n = n0 + tx;
        float val;
        if      (n < 400) val = decW[(size_t)v*400 + n];
        else if (n < 800) val = odeW2[(size_t)v*400 + (n-400)];
        else if (n == 800) val = decb[v];
        else if (n == 801) val = b2v[v];
        else               val = 0.f;
        unsigned short us = f2bf(val);
        tile[tx][v - v0] = us;
        if (n < 800) Bbf[(size_t)v*800 + n] = us;
    }
    __syncthreads();
    int vx = threadIdx.x & 63;
    int ny = threadIdx.x >> 6;
    #pragma unroll
    for (int i = 0; i < 8; ++i){
        int n = n0 + i*4 + ny;
        if (n < NO_) BbfT[(size_t)n*NT_ + v0 + vx] = tile[n - n0][vx];
    }
}

// Wxbf[400][32000] = bf16(odeW1[:,1:])
__global__ __launch_bounds__(256) void cvt_wx_k(const float* __restrict__ odeW1,
                                                unsigned short* __restrict__ Wxbf)
{
    long long idx = (long long)blockIdx.x*256 + threadIdx.x;
    if (idx >= (long long)400*NT_) return;
    int m = (int)(idx / NT_), v = (int)(idx - (long long)m*NT_);
    Wxbf[idx] = f2bf(odeW1[(size_t)m*W1S_ + 1 + v]);
}

// ---------------------------------------------------------------------------
// Fused setup: embedding gather + h0 bf16 conversions + c0 transposes.
__global__ __launch_bounds__(256) void setup_all_k(
    const int* __restrict__ tok, const float* __restrict__ emb,
    unsigned short* __restrict__ x0A,
    const float* __restrict__ h00, unsigned short* __restrict__ h0b,
    const float* __restrict__ h01, unsigned short* __restrict__ h1b,
    const float* __restrict__ h02, unsigned short* __restrict__ h2b,
    const float* __restrict__ c00, float* __restrict__ c0b,
    const float* __restrict__ c01, float* __restrict__ c1b,
    const float* __restrict__ c02, float* __restrict__ c2b)
{
    int blk = blockIdx.x;
    if (blk < 70){
        int t = blk;
        __shared__ int tk[16];
        if (threadIdx.x < 16) tk[threadIdx.x] = tok[t*16 + threadIdx.x];
        __syncthreads();
        for (int idx = threadIdx.x; idx < 16*416; idx += 256){
            int b = idx / 416, k = idx - b*416;
            float v = (k < 400) ? emb[(size_t)tk[b]*400 + k] : 0.f;
            x0A[(size_t)t*16*416 + idx] = f2bf(v);
        }
        return;
    }
    blk -= 70;
    const float* hs = nullptr; unsigned short* hd = nullptr; int Dh, SA;
    if      (blk < 72) { hs = h00; hd = h0b; Dh = 1150; SA = 1152; }
    else if (blk < 144){ hs = h01; hd = h1b; Dh = 1150; SA = 1152; blk -= 72; }
    else if (blk < 169){ hs = h02; hd = h2b; Dh = 400;  SA = 416;  blk -= 144; }
    if (hs){
        int idx = blk*256 + threadIdx.x;
        if (idx < 16*Dh){
            int b = idx / Dh, j = idx - b*Dh;
            hd[(size_t)b*SA + j] = f2bf(hs[idx]);
        }
        return;
    }
    blk -= 169;
    const float* cs; float* cd; int Dc;
    if      (blk < 72) { cs = c00; cd = c0b; Dc = 1150; }
    else if (blk < 144){ cs = c01; cd = c1b; Dc = 1150; blk -= 72; }
    else               { cs = c02; cd = c2b; Dc = 400;  blk -= 144; }
    int idx = blk*256 + threadIdx.x;
    if (idx < Dc*16){
        int j = idx >> 4, b = idx & 15;
        cd[idx] = cs[b*Dc + j];
    }
}

// ---------------------------------------------------------------------------
// K-segment dot with 4 accumulator chains.
__device__ __forceinline__ void dotseg(const unsigned short* __restrict__ a,
                                       const unsigned short* __restrict__ b,
                                       int s, int e, int kq,
                                       f32x4& c0, f32x4& c1, f32x4& c2, f32x4& c3)
{
    int k0 = s;
    for (; k0 + 128 <= e; k0 += 128){
        bf16x8 a0 = *(const bf16x8*)(a + k0 + kq);
        bf16x8 b0 = *(const bf16x8*)(b + k0 + kq);
        bf16x8 a1 = *(const bf16x8*)(a + k0 + 32 + kq);
        bf16x8 b1 = *(const bf16x8*)(b + k0 + 32 + kq);
        bf16x8 a2 = *(const bf16x8*)(a + k0 + 64 + kq);
        bf16x8 b2 = *(const bf16x8*)(b + k0 + 64 + kq);
        bf16x8 a3 = *(const bf16x8*)(a + k0 + 96 + kq);
        bf16x8 b3 = *(const bf16x8*)(b + k0 + 96 + kq);
        c0 = __builtin_amdgcn_mfma_f32_16x16x32_bf16(a0, b0, c0, 0,0,0);
        c1 = __builtin_amdgcn_mfma_f32_16x16x32_bf16(a1, b1, c1, 0,0,0);
        c2 = __builtin_amdgcn_mfma_f32_16x16x32_bf16(a2, b2, c2, 0,0,0);
        c3 = __builtin_amdgcn_mfma_f32_16x16x32_bf16(a3, b3, c3, 0,0,0);
    }
    int rem = e - k0;
    if (rem >= 32){
        bf16x8 a0 = *(const bf16x8*)(a + k0 + kq);
        bf16x8 b0 = *(const bf16x8*)(b + k0 + kq);
        c0 = __builtin_amdgcn_mfma_f32_16x16x32_bf16(a0, b0, c0, 0,0,0);
    }
    if (rem >= 64){
        bf16x8 a1 = *(const bf16x8*)(a + k0 + 32 + kq);
        bf16x8 b1 = *(const bf16x8*)(b + k0 + 32 + kq);
        c1 = __builtin_amdgcn_mfma_f32_16x16x32_bf16(a1, b1, c1, 0,0,0);
    }
    if (rem >= 96){
        bf16x8 a2 = *(const bf16x8*)(a + k0 + 64 + kq);
        bf16x8 b2 = *(const bf16x8*)(b + k0 + 64 + kq);
        c2 = __builtin_amdgcn_mfma_f32_16x16x32_bf16(a2, b2, c2, 0,0,0);
    }
}

// ---------------------------------------------------------------------------
// Upfront layer-0 x-projection: xp0[t][g*1150+j][b] = x0[t,b,:]·Wih0[g*1150+j,:]
__global__ __launch_bounds__(1024) void xproj0_k(const unsigned short* __restrict__ x0A,
                                                 const unsigned short* __restrict__ Wih0p,
                                                 unsigned short* __restrict__ xp0)
{
    int jt = blockIdx.x, t = blockIdx.y;
    int j0 = jt*16;
    int lane = threadIdx.x & 63, w = threadIdx.x >> 6;
    int gate = w & 3, seg = w >> 2;
    int am = lane & 15, kq = (lane >> 4)*8, jn = lane & 15;
    int jrow = j0 + jn; if (jrow > 1149) jrow = 1149;

    const unsigned short* ax = x0A + (size_t)t*16*416 + (size_t)am*416;
    const unsigned short* wx = Wih0p + (size_t)(gate*1150 + jrow)*416;
    int nk = 416 >> 5;
    int q0 = ((nk*seg) >> 2) << 5, q1 = ((nk*(seg+1)) >> 2) << 5;
    f32x4 c0v={0.f,0.f,0.f,0.f},c1v={0.f,0.f,0.f,0.f},c2v={0.f,0.f,0.f,0.f},c3v={0.f,0.f,0.f,0.f};
    dotseg(ax, wx, q0, q1, kq, c0v, c1v, c2v, c3v);
    f32x4 acc = (c0v + c1v) + (c2v + c3v);

    __shared__ float g16[16][16][17];
    int bm = (lane >> 4)*4;
    #pragma unroll
    for (int r = 0; r < 4; ++r) g16[w][bm + r][jn] = acc[r];
    __syncthreads();
    if (threadIdx.x < 256){
        int jl = threadIdx.x >> 4, b = threadIdx.x & 15;
        int j = j0 + jl;
        if (j < 1150){
            unsigned short* xp = xp0 + (size_t)t*4600*16;
            #pragma unroll
            for (int g = 0; g < 4; ++g){
                float s = g16[g][b][jl] + g16[g+4][b][jl] + g16[g+8][b][jl] + g16[g+12][b][jl];
                xp[((size_t)(g*1150 + j))*16 + b] = f2bf(s);
            }
        }
    }
}

// ---------------------------------------------------------------------------
// Deep-pipelined LSTM wavefront step. 266 blocks, all block-local.
__global__ __launch_bounds__(1024) void lstm_step2_k(int u,
    unsigned short* __restrict__ ys0A, unsigned short* __restrict__ ys1A,
    float* __restrict__ x3,
    unsigned short* __restrict__ h0b, float* __restrict__ c0,
    unsigned short* __restrict__ h1b, float* __restrict__ c1,
    unsigned short* __restrict__ h2b, float* __restrict__ c2,
    const unsigned short* __restrict__ Whh0p, const float* __restrict__ bih0, const float* __restrict__ bhh0,
    const unsigned short* __restrict__ Wih1p, const unsigned short* __restrict__ Whh1p,
    const float* __restrict__ bih1, const float* __restrict__ bhh1,
    const unsigned short* __restrict__ Wih2p, const unsigned short* __restrict__ Whh2p,
    const float* __restrict__ bih2, const float* __restrict__ bhh2,
    const unsigned short* __restrict__ xp0,
    unsigned short* __restrict__ xp1, unsigned short* __restrict__ xp2)
{
    int blk = blockIdx.x;
    int role, jt;
    if      (blk < 72) { role = 0; jt = blk; }
    else if (blk < 144){ role = 1; jt = blk - 72; }
    else if (blk < 216){ role = 2; jt = blk - 144; }
    else if (blk < 241){ role = 3; jt = blk - 216; }
    else               { role = 4; jt = blk - 241; }
    int t = u - role;
    if (t < 0 || t >= S_) return;
    int j0 = jt*16;

    int lane = threadIdx.x & 63, w = threadIdx.x >> 6;
    int gate = w & 3, seg = w >> 2;
    int am = lane & 15, kq = (lane >> 4)*8, jn = lane & 15;

    __shared__ float g16[16][16][17];

    if (role == 1 || role == 3){
        const unsigned short *A, *Wi; int Dh; unsigned short* xp;
        if (role == 1){ A = ys0A + (size_t)t*16*1152; Wi = Wih1p; Dh = 1150; xp = xp1 + (size_t)t*4600*16; }
        else          { A = ys1A + (size_t)t*16*1152; Wi = Wih2p; Dh = 400;  xp = xp2 + (size_t)t*1600*16; }
        int jrow = j0 + jn; if (jrow > Dh-1) jrow = Dh-1;
        const unsigned short* ax = A + (size_t)am*1152;
        const unsigned short* wx = Wi + (size_t)(gate*Dh + jrow)*1152;
        int nk = 1152 >> 5;
        int q0 = ((nk*seg) >> 2) << 5, q1 = ((nk*(seg+1)) >> 2) << 5;
        f32x4 c0v={0.f,0.f,0.f,0.f},c1v={0.f,0.f,0.f,0.f},c2v={0.f,0.f,0.f,0.f},c3v={0.f,0.f,0.f,0.f};
        dotseg(ax, wx, q0, q1, kq, c0v, c1v, c2v, c3v);
        f32x4 acc = (c0v + c1v) + (c2v + c3v);
        int bm = (lane >> 4)*4;
        #pragma unroll
        for (int r = 0; r < 4; ++r) g16[w][bm + r][jn] = acc[r];
        __syncthreads();
        if (threadIdx.x < 256){
            int jl = threadIdx.x >> 4, b = threadIdx.x & 15;
            int j = j0 + jl;
            if (j < Dh){
                #pragma unroll
                for (int g = 0; g < 4; ++g){
                    float s = g16[g][b][jl] + g16[g+4][b][jl] + g16[g+8][b][jl] + g16[g+12][b][jl];
                    xp[((size_t)(g*Dh + j))*16 + b] = f2bf(s);
                }
            }
        }
    } else {
        const unsigned short *Ah, *Wh, *xp;
        const float *bih, *bhh;
        float *cst, *x3o = nullptr;
        unsigned short *yo = nullptr, *hrec;
        int Dh, SAh, Kh;
        if (role == 0){
            Ah = h0b + (size_t)(t&1)*16*1152; SAh = 1152; Kh = 1152;
            Wh = Whh0p; bih = bih0; bhh = bhh0; Dh = 1150;
            cst = c0; hrec = h0b + (size_t)((t+1)&1)*16*1152;
            yo = ys0A + (size_t)t*16*1152;
            xp = xp0 + (size_t)t*4600*16;
        } else if (role == 2){
            Ah = h1b + (size_t)(t&1)*16*1152; SAh = 1152; Kh = 1152;
            Wh = Whh1p; bih = bih1; bhh = bhh1; Dh = 1150;
            cst = c1; hrec = h1b + (size_t)((t+1)&1)*16*1152;
            yo = ys1A + (size_t)t*16*1152;
            xp = xp1 + (size_t)t*4600*16;
        } else {
            Ah = h2b + (size_t)(t&1)*16*416; SAh = 416; Kh = 416;
            Wh = Whh2p; bih = bih2; bhh = bhh2; Dh = 400;
            cst = c2; hrec = h2b + (size_t)((t+1)&1)*16*416;
            x3o = x3 + (size_t)t*16*400;
            xp = xp2 + (size_t)t*1600*16;
        }
        int jrow = j0 + jn; if (jrow > Dh-1) jrow = Dh-1;
        const unsigned short* ah = Ah + (size_t)am*SAh;
        const unsigned short* wh = Wh + (size_t)(gate*Dh + jrow)*SAh;
        int nk = Kh >> 5;
        int q0 = ((nk*seg) >> 2) << 5, q1 = ((nk*(seg+1)) >> 2) << 5;
        f32x4 c0v={0.f,0.f,0.f,0.f},c1v={0.f,0.f,0.f,0.f},c2v={0.f,0.f,0.f,0.f},c3v={0.f,0.f,0.f,0.f};
        dotseg(ah, wh, q0, q1, kq, c0v, c1v, c2v, c3v);
        f32x4 acc = (c0v + c1v) + (c2v + c3v);
        int bm = (lane >> 4)*4;
        #pragma unroll
        for (int r = 0; r < 4; ++r) g16[w][bm + r][jn] = acc[r];
        __syncthreads();
        if (threadIdx.x < 256){
            int jl = threadIdx.x >> 4, b = threadIdx.x & 15;
            int j = j0 + jl;
            if (j < Dh){
                float pi = g16[0][b][jl] + g16[4][b][jl] + g16[8][b][jl]  + g16[12][b][jl]
                         + bfu(xp[((size_t)(0*Dh + j))*16 + b]) + bih[j]      + bhh[j];
                float pf = g16[1][b][jl] + g16[5][b][jl] + g16[9][b][jl]  + g16[13][b][jl]
                         + bfu(xp[((size_t)(1*Dh + j))*16 + b]) + bih[Dh+j]   + bhh[Dh+j];
                float pg = g16[2][b][jl] + g16[6][b][jl] + g16[10][b][jl] + g16[14][b][jl]
                         + bfu(xp[((size_t)(2*Dh + j))*16 + b]) + bih[2*Dh+j] + bhh[2*Dh+j];
                float po = g16[3][b][jl] + g16[7][b][jl] + g16[11][b][jl] + g16[15][b][jl]
                         + bfu(xp[((size_t)(3*Dh + j))*16 + b]) + bih[3*Dh+j] + bhh[3*Dh+j];
                float cold = cst[j*16 + b];
                float cnew = sigm(pf)*cold + sigm(pi)*tanhf(pg);
                float h    = sigm(po)*tanhf(cnew);
                cst[j*16 + b] = cnew;
                unsigned short hb16 = f2bf(h);
                hrec[(size_t)b*SAh + j] = hb16;
                if (yo)  yo[(size_t)b*1152 + j] = hb16;
                if (x3o) x3o[(size_t)b*400 + j] = h;
            }
        }
    }
}

// ---------------------------------------------------------------------------
// MFMA ODE precompute, LDS stride 44, 16 K-slabs, N=802 (incl dvec/bvec cols),
// XCD-chunked block swizzle (448 blocks, 448%8==0).
__global__ __launch_bounds__(256) void gemm_odeT_k(
    const unsigned short* __restrict__ Wxbf,
    const unsigned short* __restrict__ BbfT,
    float* __restrict__ partials)
{
    __shared__ unsigned short As[128*44];
    __shared__ unsigned short Bs[128*44];
    int lin = blockIdx.x + 7*(blockIdx.y + 4*blockIdx.z);   // [0,448)
    int swz = (lin & 7)*56 + (lin >> 3);
    int xt = swz % 7, rem = swz / 7;
    int yt = rem & 3, zt = rem >> 2;
    int n0 = xt*128, m0 = yt*128, v0 = zt*2000;
    int tid = threadIdx.x;
    int lane = tid & 63, wid = tid >> 6;
    int wr = wid >> 1, wc = wid & 1;
    f32x4 acc[4][4] = {};

    int srow = tid >> 1;
    int sk   = (tid & 1) * 16;
    int mL = m0 + srow; if (mL > 399) mL = 399;
    int nL = n0 + srow; if (nL > NO_-1) nL = NO_-1;
    const unsigned short* ap = Wxbf + (size_t)mL*NT_ + v0 + sk;
    const unsigned short* bp = BbfT + (size_t)nL*NT_ + v0 + sk;

    for (int k0 = 0; k0 < 2000; k0 += 32){
        uint4 av0 = *(const uint4*)(ap + k0);
        uint4 av1 = *(const uint4*)(ap + k0 + 8);
        uint4 bv0 = *(const uint4*)(bp + k0);
        uint4 bv1 = *(const uint4*)(bp + k0 + 8);

        __syncthreads();
        *(uint4*)&As[srow*44 + sk]     = av0;
        *(uint4*)&As[srow*44 + sk + 8] = av1;
        *(uint4*)&Bs[srow*44 + sk]     = bv0;
        *(uint4*)&Bs[srow*44 + sk + 8] = bv1;
        __syncthreads();

        int kq = (lane >> 4) * 8;
        int rA = wr*64 + (lane & 15);
        int rB = wc*64 + (lane & 15);
        bf16x8 af[4], bfv[4];
        #pragma unroll
        for (int f = 0; f < 4; ++f){
            af[f]  = *(const bf16x8*)&As[(rA + f*16)*44 + kq];
            bfv[f] = *(const bf16x8*)&Bs[(rB + f*16)*44 + kq];
        }
        #pragma unroll
        for (int fm = 0; fm < 4; ++fm)
            #pragma unroll
            for (int fn = 0; fn < 4; ++fn)
                acc[fm][fn] = __builtin_amdgcn_mfma_f32_16x16x32_bf16(af[fm], bfv[fn], acc[fm][fn], 0, 0, 0);
    }

    float* op = partials + (size_t)zt*400*NOS;
    int cm = (lane >> 4) * 4;
    int cn = lane & 15;
    #pragma unroll
    for (int fm = 0; fm < 4; ++fm){
        int mrow0 = m0 + wr*64 + fm*16 + cm;
        #pragma unroll
        for (int fn = 0; fn < 4; ++fn){
            int n = n0 + wc*64 + fn*16 + cn;
            if (n >= NO_) continue;
            #pragma unroll
            for (int r = 0; r < 4; ++r){
                int mr = mrow0 + r;
                if (mr < 400) op[mr*NOS + n] = acc[fm][fn][r];
            }
        }
    }
}

// sum 16 slabs; scatter: n<400 -> Qbf, 400..799 -> Pbf, 800 -> dvec, 801 -> bvec.
__global__ __launch_bounds__(256) void reduce16v_k(const float* __restrict__ p,
                                                   const float* __restrict__ odeW1,
                                                   unsigned short* __restrict__ Qbf,
                                                   unsigned short* __restrict__ Pbf,
                                                   float* __restrict__ dvec,
                                                   float* __restrict__ bvec,
                                                   float* __restrict__ wtd)
{
    int i = blockIdx.x*256 + threadIdx.x;
    if (i < 400) wtd[i] = odeW1[(size_t)i*W1S_];
    if (i >= 400*NO_) return;
    int m = i / NO_, n = i - m*NO_;
    float s = 0.f;
    #pragma unroll
    for (int k = 0; k < 16; ++k) s += p[(size_t)k*400*NOS + m*NOS + n];
    if      (n < 400) Qbf[m*416 + n] = f2bf(s);
    else if (n < 800) Pbf[m*416 + (n-400)] = f2bf(s);
    else if (n == 800) dvec[m] = s;
    else               bvec[m] = s;
}

// ---------------------------------------------------------------------------
// FUSED ODE: G0 GEMM + 2 RK4 steps + Gy update + Abf output.
__global__ __launch_bounds__(512) void ode_rk4_k(
    const float* __restrict__ x3,
    const unsigned short* __restrict__ Qbf,
    const unsigned short* __restrict__ Pbf,
    const float* __restrict__ dvec, const float* __restrict__ bvec,
    const float* __restrict__ wtd, const float* __restrict__ b1,
    unsigned short* __restrict__ Abf)
{
    __shared__ unsigned short Al[16*AST];
    int m0 = blockIdx.x*16;
    int tid = threadIdx.x;
    int lane = tid & 63, ng = tid >> 6;
    int cm = (lane >> 4)*4;
    int cn = lane & 15;
    int kq = (lane >> 4)*8;

    #pragma unroll
    for (int i = 0; i < 13; ++i){
        int idx = i*512 + tid;
        if (idx < 6400){
            int m = idx / 400, k = idx - m*400;
            unsigned short us = f2bf(x3[(size_t)(m0+m)*400 + k]);
            Al[m*AST + k] = us;
            Abf[(size_t)(m0+m)*800 + k] = us;
        }
    }
    if (tid < 256){ Al[(tid>>4)*AST + 400 + (tid & 15)] = 0; }
    __syncthreads();

    float gy[4][4], hacc[4][4], comb[4][4];
    float vd[4], vb[4], vw[4], v1[4];
    #pragma unroll
    for (int i = 0; i < 4; ++i){
        int nt = ng + 8*i;
        if (nt < 25){
            int n = nt*16 + cn;
            vd[i] = dvec[n]; vb[i] = bvec[n]; vw[i] = wtd[n]; v1[i] = b1[n];
        } else { vd[i]=0.f; vb[i]=0.f; vw[i]=0.f; v1[i]=0.f; }
        #pragma unroll
        for (int r = 0; r < 4; ++r) hacc[i][r] = 0.f;
    }

    const unsigned short* arow = &Al[(size_t)cn*AST + kq];
    f32x4 t4[4];
    auto gemmB = [&](const unsigned short* Bb){
        #pragma unroll
        for (int i = 0; i < 4; ++i){
            f32x4 a = {0.f,0.f,0.f,0.f};
            int nt = ng + 8*i;
            if (nt < 25){
                const unsigned short* brow = Bb + (size_t)(nt*16 + cn)*416 + kq;
                #pragma unroll
                for (int k0 = 0; k0 < 416; k0 += 32){
                    bf16x8 av = *(const bf16x8*)(arow + k0);
                    bf16x8 bv = *(const bf16x8*)(brow + k0);
                    a = __builtin_amdgcn_mfma_f32_16x16x32_bf16(av, bv, a, 0,0,0);
                }
            }
            t4[i] = a;
        }
    };
    auto writeA = [&](float vals[4][4]){
        __syncthreads();
        #pragma unroll
        for (int i = 0; i < 4; ++i){
            int nt = ng + 8*i;
            if (nt < 25){
                int n = nt*16 + cn;
                #pragma unroll
                for (int r = 0; r < 4; ++r)
                    Al[(cm + r)*AST + n] = f2bf(vals[i][r]);
            }
        }
        __syncthreads();
    };

    gemmB(Qbf);
    #pragma unroll
    for (int i = 0; i < 4; ++i)
        #pragma unroll
        for (int r = 0; r < 4; ++r) gy[i][r] = t4[i][r] + vd[i];

    const float dt = 0.5f;
    for (int st = 0; st < 2; ++st){
        float t0 = st * dt;
        float hs[4][4];
        #pragma unroll
        for (int i = 0; i < 4; ++i)
            #pragma unroll
            for (int r = 0; r < 4; ++r){
                float v = softplusf(gy[i][r] + t0*vw[i] + v1[i]);
                hs[i][r] = v; comb[i][r] = v;
            }
        writeA(hs);
        gemmB(Pbf);
        #pragma unroll
        for (int i = 0; i < 4; ++i)
            #pragma unroll
            for (int r = 0; r < 4; ++r){
                float v = softplusf(0.25f*t4[i][r] + gy[i][r] + 0.25f*vb[i] + (t0+0.25f)*vw[i] + v1[i]);
                hs[i][r] = v; comb[i][r] += 2.f*v;
            }
        writeA(hs);
        gemmB(Pbf);
        #pragma unroll
        for (int i = 0; i < 4; ++i)
            #pragma unroll
            for (int r = 0; r < 4; ++r){
                float v = softplusf(0.25f*t4[i][r] + gy[i][r] + 0.25f*vb[i] + (t0+0.25f)*vw[i] + v1[i]);
                hs[i][r] = v; comb[i][r] += 2.f*v;
            }
        writeA(hs);
        gemmB(Pbf);
        #pragma unroll
        for (int i = 0; i < 4; ++i)
            #pragma unroll
            for (int r = 0; r < 4; ++r){
                float v = softplusf(0.5f*t4[i][r] + gy[i][r] + 0.5f*vb[i] + (t0+0.5f)*vw[i] + v1[i]);
                comb[i][r] += v;
            }
        #pragma unroll
        for (int i = 0; i < 4; ++i)
            #pragma unroll
            for (int r = 0; r < 4; ++r){
                float v = comb[i][r] * (1.f/12.f);
                comb[i][r] = v;
                hacc[i][r] += v;
            }
        if (st == 0){
            writeA(comb);
            gemmB(Pbf);
            #pragma unroll
            for (int i = 0; i < 4; ++i)
                #pragma unroll
                for (int r = 0; r < 4; ++r) gy[i][r] += t4[i][r] + dt*vb[i];
        }
    }

    #pragma unroll
    for (int i = 0; i < 4; ++i){
        int nt = ng + 8*i;
        if (nt < 25){
            int n = nt*16 + cn;
            #pragma unroll
            for (int r = 0; r < 4; ++r){
                int m = m0 + cm + r;
                Abf[(size_t)m*800 + 400 + n] = f2bf(hacc[i][r]);
            }
        }
    }
}

// ---------------------------------------------------------------------------
// MFMA decode, 256x128 tiles, LDS stride 44, natural n-fastest grid (best
// measured: round-14; both locality remaps regressed), bf16 output zb.
__global__ __launch_bounds__(512) void decode_mfma_k(
    const unsigned short* __restrict__ Abf,
    const unsigned short* __restrict__ Bbf,
    const float* __restrict__ decb, const float* __restrict__ b2v,
    unsigned short* __restrict__ zb)
{
    __shared__ unsigned short As[256*44];
    __shared__ unsigned short Bs[128*44];
    int n0 = blockIdx.x*128, m0 = blockIdx.y*256;
    int tid = threadIdx.x;
    int lane = tid & 63, wid = tid >> 6;
    int wr = wid >> 1, wc = wid & 1;
    f32x4 acc[4][4] = {};

    int srA = tid >> 1, skA = (tid & 1)*16;
    int srB = tid >> 2, skB = (tid & 3)*8;

    for (int k0 = 0; k0 < 800; k0 += 32){
        uint4 av0 = {0,0,0,0}, av1 = {0,0,0,0};
        int m = m0 + srA;
        if (m < SB_){
            const uint4* ap = (const uint4*)(Abf + (size_t)m*800 + k0 + skA);
            av0 = ap[0]; av1 = ap[1];
        }
        uint4 bv = *(const uint4*)(Bbf + (size_t)(n0 + srB)*800 + k0 + skB);

        __syncthreads();
        *(uint4*)&As[srA*44 + skA]     = av0;
        *(uint4*)&As[srA*44 + skA + 8] = av1;
        *(uint4*)&Bs[srB*44 + skB]     = bv;
        __syncthreads();

        int kq = (lane >> 4) * 8;
        int rA = wr*64 + (lane & 15);
        int rB = wc*64 + (lane & 15);
        bf16x8 af[4], bfv[4];
        #pragma unroll
        for (int f = 0; f < 4; ++f){
            af[f]  = *(const bf16x8*)&As[(rA + f*16)*44 + kq];
            bfv[f] = *(const bf16x8*)&Bs[(rB + f*16)*44 + kq];
        }
        #pragma unroll
        for (int fm = 0; fm < 4; ++fm)
            #pragma unroll
            for (int fn = 0; fn < 4; ++fn)
                acc[fm][fn] = __builtin_amdgcn_mfma_f32_16x16x32_bf16(af[fm], bfv[fn], acc[fm][fn], 0, 0, 0);
    }

    int cm = (lane >> 4) * 4;
    int cn = lane & 15;
    #pragma unroll
    for (int fm = 0; fm < 4; ++fm){
        int mrow0 = m0 + wr*64 + fm*16 + cm;
        #pragma unroll
        for (int fn = 0; fn < 4; ++fn){
            int n = n0 + wc*64 + fn*16 + cn;
            float db = decb[n] + b2v[n];
            #pragma unroll
            for (int r = 0; r < 4; ++r){
                int mr = mrow0 + r;
                if (mr < SB_) zb[(size_t)mr*NT_ + n] = f2bf(acc[fm][fn][r] + db);
            }
        }
    }
}

// ---------------------------------------------------------------------------
// Fused log-softmax: reads bf16 zb, row resident in registers, writes fp32 out.
__global__ __launch_bounds__(1024) void softmax_k(const unsigned short* __restrict__ zb,
                                                  float* __restrict__ zout)
{
    int r = blockIdx.x;
    const unsigned short* zr = zb + (size_t)r*NT_;
    float* zo = zout + (size_t)r*NT_;
    int tid = threadIdx.x;
    __shared__ float sm[1024];
    float4 v[8];
    float mx = -1e30f;
    #pragma unroll
    for (int i = 0; i < 8; ++i){
        int base = i*4096 + tid*4;
        if (base < NT_){
            ushort4 u = *(const ushort4*)(zr + base);
            v[i].x = bfu(u.x); v[i].y = bfu(u.y); v[i].z = bfu(u.z); v[i].w = bfu(u.w);
            mx = fmaxf(mx, fmaxf(fmaxf(v[i].x, v[i].y), fmaxf(v[i].z, v[i].w)));
        } else {
            v[i].x = v[i].y = v[i].z = v[i].w = 0.f;
        }
    }
    sm[tid] = mx; __syncthreads();
    for (int s = 512; s > 0; s >>= 1){
        if (tid < s) sm[tid] = fmaxf(sm[tid], sm[tid+s]);
        __syncthreads();
    }
    mx = sm[0]; __syncthreads();
    float sum = 0.f;
    #pragma unroll
    for (int i = 0; i < 8; ++i){
        int base = i*4096 + tid*4;
        if (base < NT_){
            sum += __expf(v[i].x - mx) + __expf(v[i].y - mx)
                 + __expf(v[i].z - mx) + __expf(v[i].w - mx);
        }
    }
    sm[tid] = sum; __syncthreads();
    for (int s = 512; s > 0; s >>= 1){
        if (tid < s) sm[tid] += sm[tid+s];
        __syncthreads();
    }
    float sinv = 1.f / sm[0];
    #pragma unroll
    for (int i = 0; i < 8; ++i){
        int base = i*4096 + tid*4;
        if (base < NT_){
            float4 o;
            o.x = logf(__expf(v[i].x - mx)*sinv + 1e-8f);
            o.y = logf(__expf(v[i].y - mx)*sinv + 1e-8f);
            o.z = logf(__expf(v[i].z - mx)*sinv + 1e-8f);
            o.w = logf(__expf(v[i].w - mx)*sinv + 1e-8f);
            *(float4*)(zo + base) = o;
        }
    }
}

// ---------------------------------------------------------------------------
extern "C" void kernel_launch(void* const* d_in, const int* in_sizes, int n_in,
                              void* d_out, int out_size, void* d_ws, size_t ws_size,
                              hipStream_t stream)
{
    const int*   tokens = (const int*)  d_in[0];
    const float* h0_0 = (const float*)d_in[1];
    const float* c0_0 = (const float*)d_in[2];
    const float* Wih0 = (const float*)d_in[3];
    const float* Whh0 = (const float*)d_in[4];
    const float* bih0 = (const float*)d_in[5];
    const float* bhh0 = (const float*)d_in[6];
    const float* h0_1 = (const float*)d_in[7];
    const float* c0_1 = (const float*)d_in[8];
    const float* Wih1 = (const float*)d_in[9];
    const float* Whh1 = (const float*)d_in[10];
    const float* bih1 = (const float*)d_in[11];
    const float* bhh1 = (const float*)d_in[12];
    const float* h0_2 = (const float*)d_in[13];
    const float* c0_2 = (const float*)d_in[14];
    const float* Wih2 = (const float*)d_in[15];
    const float* Whh2 = (const float*)d_in[16];
    const float* bih2 = (const float*)d_in[17];
    const float* bhh2 = (const float*)d_in[18];
    const float* emb  = (const float*)d_in[19];
    const float* decW = (const float*)d_in[20];
    const float* decb = (const float*)d_in[21];
    const float* odeW1= (const float*)d_in[22];
    const float* odeb1= (const float*)d_in[23];
    const float* odeW2= (const float*)d_in[24];
    const float* odeb2= (const float*)d_in[25];

    // workspace carve-up, all chunks 16B-aligned (~226 MB)
    float* w = (float*)d_ws;
    size_t off = 0;
    auto alloc = [&](size_t n){ float* p = w + off; off += n; return p; };
    auto allocU = [&](size_t nUsh){ return (unsigned short*)alloc(nUsh/2); };
    unsigned short* x0A  = allocU((size_t)S_*16*416);
    unsigned short* ys0A = allocU((size_t)S_*16*1152);
    unsigned short* ys1A = allocU((size_t)S_*16*1152);
    float* x3   = alloc((size_t)SB_*400);
    unsigned short* h0b = allocU((size_t)2*16*1152); float* c0b = alloc(1152*16);
    unsigned short* h1b = allocU((size_t)2*16*1152); float* c1b = alloc(1152*16);
    unsigned short* h2b = allocU((size_t)2*16*416);  float* c2b = alloc(416*16);
    unsigned short* Qbf = allocU((size_t)416*416);
    unsigned short* Pbf = allocU((size_t)416*416);
    float* dvec = alloc(512);
    float* bvec = alloc(512);
    float* wtd  = alloc(512);
    unsigned short* xp0 = allocU((size_t)S_*4600*16);
    unsigned short* xp1 = allocU((size_t)S_*4600*16);
    unsigned short* xp2 = allocU((size_t)S_*1600*16);
    float* partials = alloc((size_t)16*400*NOS);
    unsigned short* Wih0p = allocU((size_t)4600*416);
    unsigned short* Whh0p = allocU((size_t)4600*1152);
    unsigned short* Wih1p = allocU((size_t)4600*1152);
    unsigned short* Whh1p = allocU((size_t)4600*1152);
    unsigned short* Wih2p = allocU((size_t)1600*1152);
    unsigned short* Whh2p = allocU((size_t)1600*416);
    unsigned short* Abf   = allocU((size_t)SB_*800);
    unsigned short* Bbf   = allocU((size_t)NT_*800);
    unsigned short* BbfT  = allocU((size_t)808*NT_);   // 802 rows used (+pad)
    unsigned short* Wxbf  = allocU((size_t)400*NT_);
    (void)ws_size; (void)in_sizes; (void)n_in; (void)out_size;

    // bf16 logits buffer aliases BbfT+Wxbf (dead after reduce16v): 71.7 MB < 77.4 MB
    unsigned short* zb = BbfT;

    float* zout = (float*)d_out;

    // zero pad-sensitive buffers (MFMA reads pads; must not be NaN)
    hipMemsetAsync(ys0A, 0, (size_t)S_*16*1152*2, stream);
    hipMemsetAsync(ys1A, 0, (size_t)S_*16*1152*2, stream);
    hipMemsetAsync(h0b,  0, (size_t)2*16*1152*2, stream);
    hipMemsetAsync(h1b,  0, (size_t)2*16*1152*2, stream);
    hipMemsetAsync(h2b,  0, (size_t)2*16*416*2, stream);
    hipMemsetAsync(Qbf,  0, (size_t)416*416*2, stream);
    hipMemsetAsync(Pbf,  0, (size_t)416*416*2, stream);

    // weight conversions (bf16, K zero-padded): all six in one launch
    auto cvtgrid = [](long long n){ return (unsigned)((n + 255) / 256); };
    cvt_pack_all_k<<<dim3(cvtgrid((long long)4600*1152), 6), 256, 0, stream>>>(
        Wih0, Wih0p, Whh0, Whh0p, Wih1, Wih1p, Whh1, Whh1p, Wih2, Wih2p, Whh2, Whh2p);
    cvt_catB2_k<<<dim3(500, 26), 256, 0, stream>>>(decW, odeW2, decb, odeb2, Bbf, BbfT);
    cvt_wx_k<<<cvtgrid((long long)400*NT_), 256, 0, stream>>>(odeW1, Wxbf);

    // fused setup: embed + h0 bf16 + c0 transpose (one launch)
    setup_all_k<<<408, 256, 0, stream>>>(tokens, emb, x0A,
        h0_0, h0b, h0_1, h1b, h0_2, h2b, c0_0, c0b, c0_1, c1b, c0_2, c2b);

    // upfront layer-0 input projections (all t, fully parallel)
    xproj0_k<<<dim3(72, 70), 1024, 0, stream>>>(x0A, Wih0p, xp0);

    // deep-pipelined LSTM wavefront: 5 stages, 266 blocks, block-local only
    for (int u = 0; u < S_ + 4; ++u)
        lstm_step2_k<<<266, 1024, 0, stream>>>(u, ys0A, ys1A, x3,
            h0b, c0b, h1b, c1b, h2b, c2b,
            Whh0p, bih0, bhh0, Wih1p, Whh1p, bih1, bhh1, Wih2p, Whh2p, bih2, bhh2,
            xp0, xp1, xp2);

    // ODE precompute: [Q|P|dvec|bvec] = Wx @ BbfT^T via MFMA (N=802), 16 K-slabs
    gemm_odeT_k<<<dim3(7,4,16), 256, 0, stream>>>(Wxbf, BbfT, partials);
    reduce16v_k<<<(400*NO_+255)/256, 256, 0, stream>>>(partials, odeW1, Qbf, Pbf, dvec, bvec, wtd);

    // Fused ODE: G0 + RK4(2 steps) + Abf (both halves) in one kernel
    ode_rk4_k<<<70, 512, 0, stream>>>(x3, Qbf, Pbf, dvec, bvec, wtd, odeb1, Abf);

    // MFMA decode (256x128 tiles, bf16 out, n-fastest grid) + log-softmax
    decode_mfma_k<<<dim3(250,5), 512, 0, stream>>>(Abf, Bbf, decb, odeb2, zb);
    softmax_k<<<SB_, 1024, 0, stream>>>(zb, zout);
}